// Round 8
// baseline (235.769 us; speedup 1.0000x reference)
//
#include <hip/hip_runtime.h>
#include <math.h>

#define EDIM   1024
#define KVEDIM 256
#define HDIM   64
#define QHEADS 16
#define NSEG   2

typedef __attribute__((ext_vector_type(8))) short short8;   // 8 bf16 (4 VGPRs)
typedef __attribute__((ext_vector_type(4))) float f32x4;

// fp32 -> bf16 (RNE)
__device__ __forceinline__ unsigned pack2(float a, float b) {
    unsigned ua = __builtin_bit_cast(unsigned, a);
    unsigned ub = __builtin_bit_cast(unsigned, b);
    ua += 0x7fffu + ((ua >> 16) & 1u);
    ub += 0x7fffu + ((ub >> 16) & 1u);
    return (ua >> 16) | (ub & 0xffff0000u);
}
__device__ __forceinline__ short f2b(float a) {
    unsigned ua = __builtin_bit_cast(unsigned, a);
    ua += 0x7fffu + ((ua >> 16) & 1u);
    return (short)(ua >> 16);
}

#if __has_builtin(__builtin_amdgcn_exp2f)
__device__ __forceinline__ float fexp2(float x) { return __builtin_amdgcn_exp2f(x); }
#else
__device__ __forceinline__ float fexp2(float x) { return exp2f(x); }
#endif

// ===========================================================================
// Kernel 1: fp32 -> bf16 conversion (grid-stride streaming, ~67 MB traffic).
// ===========================================================================
__global__ __launch_bounds__(256)
void cvt_bf16(const float* __restrict__ query, const float* __restrict__ key,
              const float* __restrict__ value,
              const float* __restrict__ Wq, const float* __restrict__ Wk,
              const float* __restrict__ Wv,
              short* __restrict__ qa, short* __restrict__ ka, short* __restrict__ va,
              short* __restrict__ wqb, short* __restrict__ wkb, short* __restrict__ wvb,
              int n)
{
    const int base = ((int)blockIdx.x * 256 + (int)threadIdx.x) * 8;
    const int stride = (int)gridDim.x * 256 * 8;
    auto cvt_one = [&](const float* __restrict__ s, short* __restrict__ d, int nn) {
        for (int i = base; i < nn; i += stride) {
            float4 x = *(const float4*)&s[i];
            float4 y = *(const float4*)&s[i + 4];
            uint4 o;
            o.x = pack2(x.x, x.y); o.y = pack2(x.z, x.w);
            o.z = pack2(y.x, y.y); o.w = pack2(y.z, y.w);
            *(uint4*)&d[i] = o;
        }
    };
    cvt_one(query, qa, n * EDIM);
    cvt_one(key,   ka, n * EDIM);
    cvt_one(value, va, n * EDIM);
    cvt_one(Wq, wqb, EDIM * EDIM);
    cvt_one(Wk, wkb, KVEDIM * EDIM);
    cvt_one(Wv, wvb, KVEDIM * EDIM);
}

// ===========================================================================
// Kernel 2: projection GEMMs. 384 tiles of 64x128, BK=64, register prefetch.
// [0,256) q, [256,320) k, [320,384) v.  (validated inside R7's mega run)
// ===========================================================================
__global__ __launch_bounds__(256)
void proj_gemm(const short* __restrict__ qa, const short* __restrict__ ka,
               const short* __restrict__ va,
               const short* __restrict__ wqb, const short* __restrict__ wkb,
               const short* __restrict__ wvb,
               const float* __restrict__ bq, const float* __restrict__ bk,
               const float* __restrict__ bv,
               short* __restrict__ qb, short* __restrict__ kb,
               short* __restrict__ vb, float qscale)
{
    __shared__ __align__(16) short sm[13824];
    const int t = threadIdx.x, lane = t & 63, wvv = t >> 6;
    const int lm = lane & 15, quad = lane >> 4;
    const int q8 = quad * 8, q4 = quad * 4;
    const int wm = (wvv & 1) * 32, wn = (wvv >> 1) * 64;

    short* As = sm;            // 64 x 72
    short* Ws = sm + 4608;     // 128 x 72

    const int ar = t >> 2, acol = (t & 3) * 16;
    const int wr = t >> 1, wcol = (t & 1) * 32;

    const int tile = blockIdx.x;
    const short* A; const short* W; const float* bias; short* C;
    int N, bm, bn; float scale;
    if (tile < 256) {
        A = qa; W = wqb; bias = bq; C = qb; N = EDIM; scale = qscale;
        bm = (tile >> 3) * 64; bn = (tile & 7) * 128;
    } else if (tile < 320) {
        int i = tile - 256;
        A = ka; W = wkb; bias = bk; C = kb; N = KVEDIM; scale = 1.0f;
        bm = (i >> 1) * 64; bn = (i & 1) * 128;
    } else {
        int i = tile - 320;
        A = va; W = wvb; bias = bv; C = vb; N = KVEDIM; scale = 1.0f;
        bm = (i >> 1) * 64; bn = (i & 1) * 128;
    }

    const short* Ab = A + (size_t)(bm + ar) * EDIM + acol;
    const short* Wb = W + (size_t)(bn + wr) * EDIM + wcol;

    f32x4 acc[2][4];
    #pragma unroll
    for (int i = 0; i < 2; ++i)
        #pragma unroll
        for (int j = 0; j < 4; ++j) acc[i][j] = {0.f, 0.f, 0.f, 0.f};

    uint4 pa0 = *(const uint4*)(Ab);
    uint4 pa1 = *(const uint4*)(Ab + 8);
    uint4 pw0 = *(const uint4*)(Wb);
    uint4 pw1 = *(const uint4*)(Wb + 8);
    uint4 pw2 = *(const uint4*)(Wb + 16);
    uint4 pw3 = *(const uint4*)(Wb + 24);

    for (int k0 = 0; k0 < EDIM; k0 += 64) {
        __syncthreads();
        *(uint4*)&As[ar * 72 + acol]      = pa0;
        *(uint4*)&As[ar * 72 + acol + 8]  = pa1;
        *(uint4*)&Ws[wr * 72 + wcol]      = pw0;
        *(uint4*)&Ws[wr * 72 + wcol + 8]  = pw1;
        *(uint4*)&Ws[wr * 72 + wcol + 16] = pw2;
        *(uint4*)&Ws[wr * 72 + wcol + 24] = pw3;
        __syncthreads();
        if (k0 + 64 < EDIM) {
            pa0 = *(const uint4*)(Ab + k0 + 64);
            pa1 = *(const uint4*)(Ab + k0 + 72);
            pw0 = *(const uint4*)(Wb + k0 + 64);
            pw1 = *(const uint4*)(Wb + k0 + 72);
            pw2 = *(const uint4*)(Wb + k0 + 80);
            pw3 = *(const uint4*)(Wb + k0 + 88);
        }
        #pragma unroll
        for (int ks = 0; ks < 2; ++ks) {
            short8 af[2], wf[4];
            #pragma unroll
            for (int i = 0; i < 2; ++i)
                af[i] = *(const short8*)&As[(wm + i * 16 + lm) * 72 + ks * 32 + q8];
            #pragma unroll
            for (int j = 0; j < 4; ++j)
                wf[j] = *(const short8*)&Ws[(wn + j * 16 + lm) * 72 + ks * 32 + q8];
            #pragma unroll
            for (int i = 0; i < 2; ++i)
                #pragma unroll
                for (int j = 0; j < 4; ++j)
                    acc[i][j] = __builtin_amdgcn_mfma_f32_16x16x32_bf16(
                        af[i], wf[j], acc[i][j], 0, 0, 0);
        }
    }

    #pragma unroll
    for (int j = 0; j < 4; ++j) {
        float bj = bias[bn + wn + j * 16 + lm];
        #pragma unroll
        for (int i = 0; i < 2; ++i)
            #pragma unroll
            for (int r = 0; r < 4; ++r)
                C[(size_t)(bm + wm + i * 16 + q4 + r) * N + bn + wn + j * 16 + lm] =
                    f2b((acc[i][j][r] + bj) * scale);
    }
}

// ===========================================================================
// Kernel 3: transpose v-proj (n x 256 bf16) -> vt (256 x n bf16).
// Thread handles a 4s x 4c block via in-register unpack (no LDS).
// grid = 128: (b&31) s-tile of 64, (b>>5) c-tile of 64.
// ===========================================================================
__global__ __launch_bounds__(256)
void vt_kernel(const short* __restrict__ vb, short* __restrict__ vt, int n)
{
    const int t = threadIdx.x;
    const int s4 = ((int)blockIdx.x & 31) * 64 + (t & 15) * 4;
    const int c4 = ((int)blockIdx.x >> 5) * 64 + (t >> 4) * 4;

    uint2 vr[4];
    #pragma unroll
    for (int i = 0; i < 4; ++i)
        vr[i] = *(const uint2*)&vb[(size_t)(s4 + i) * KVEDIM + c4];
    #pragma unroll
    for (int j = 0; j < 4; ++j) {
        int w = j >> 1, hi = (j & 1) * 16;
        unsigned e0 = (vr[0].x * (w == 0) + vr[0].y * (w == 1)) ;
        // (avoid mul trick; do it plainly)
        unsigned a0 = w ? vr[0].y : vr[0].x;
        unsigned a1 = w ? vr[1].y : vr[1].x;
        unsigned a2 = w ? vr[2].y : vr[2].x;
        unsigned a3 = w ? vr[3].y : vr[3].x;
        unsigned f0 = (a0 >> hi) & 0xffffu;
        unsigned f1 = (a1 >> hi) & 0xffffu;
        unsigned f2 = (a2 >> hi) & 0xffffu;
        unsigned f3 = (a3 >> hi) & 0xffffu;
        uint2 o; o.x = f0 | (f1 << 16); o.y = f2 | (f3 << 16);
        *(uint2*)&vt[(size_t)(c4 + j) * n + s4] = o;
        (void)e0;
    }
}

// ===========================================================================
// Kernel 4: BARRIER-FREE wave-private MFMA flash attention.
// grid (32, 16, NSEG); block = 4 waves; wave owns 16 q-rows end-to-end.
// K and V^T fragments loaded DIRECTLY from global (L2-resident, no staging).
// P transform via wave-private LDS (no __syncthreads anywhere).
// Max-free softmax (log2e folded into q). Emits unnormalized O + denom l.
// ===========================================================================
__global__ __launch_bounds__(256, 4)
void attn_wave(const short* __restrict__ qb, const short* __restrict__ kb,
               const short* __restrict__ vt, float* __restrict__ Opart,
               float* __restrict__ Lpart, int n)
{
    __shared__ __align__(16) short Ps[4 * 16 * 72];   // per-wave P buffers

    const int t = threadIdx.x, lane = t & 63, wv = t >> 6;
    const int lm = lane & 15, quad = lane >> 4;
    const int q8 = quad * 8, q4 = quad * 4;
    const int qh = blockIdx.y, kvh = qh >> 2;
    const int seg = blockIdx.z;
    const int segkeys = n / NSEG;
    const int sbeg = seg * segkeys;
    const int row0 = (int)blockIdx.x * 64 + wv * 16;   // wave's first q-row

    short* Psw = Ps + wv * (16 * 72);

    // Q B-fragments (one q-row per lane), reused all chunks
    const short* qrowp = &qb[(size_t)(row0 + lm) * EDIM + qh * HDIM];
    short8 qf0 = *(const short8*)&qrowp[q8];
    short8 qf1 = *(const short8*)&qrowp[32 + q8];

    f32x4 zero = {0.f, 0.f, 0.f, 0.f};
    f32x4 oacc[4] = {zero, zero, zero, zero};
    float lp = 0.f;

    for (int c = 0; c < segkeys; c += 64) {
        const int s0 = sbeg + c;

        // ---- QK^T (swapped): S'[key][qrow]; K A-frags direct from global ----
        short8 kf[4][2];
        #pragma unroll
        for (int nt = 0; nt < 4; ++nt) {
            const short* kr = &kb[(size_t)(s0 + nt * 16 + lm) * KVEDIM + kvh * HDIM];
            kf[nt][0] = *(const short8*)&kr[q8];
            kf[nt][1] = *(const short8*)&kr[32 + q8];
        }
        #pragma unroll
        for (int nt = 0; nt < 4; ++nt) {
            f32x4 s = zero;
            s = __builtin_amdgcn_mfma_f32_16x16x32_bf16(kf[nt][0], qf0, s, 0, 0, 0);
            s = __builtin_amdgcn_mfma_f32_16x16x32_bf16(kf[nt][1], qf1, s, 0, 0, 0);
            float p0 = fexp2(s[0]);
            float p1 = fexp2(s[1]);
            float p2 = fexp2(s[2]);
            float p3 = fexp2(s[3]);
            lp += (p0 + p1) + (p2 + p3);
            uint2 pw; pw.x = pack2(p0, p1); pw.y = pack2(p2, p3);
            // lane holds keys (quad*4..+3) of q-row lm -> b64 write, wave-private
            *(uint2*)&Psw[lm * 72 + nt * 16 + q4] = pw;
        }

        // ---- PV: P A-frags from own LDS; V^T frags direct from global ----
        short8 pf0 = *(const short8*)&Psw[lm * 72 + q8];
        short8 pf1 = *(const short8*)&Psw[lm * 72 + 32 + q8];
        #pragma unroll
        for (int dt = 0; dt < 4; ++dt) {
            const short* vr = &vt[(size_t)(kvh * HDIM + dt * 16 + lm) * n + s0];
            short8 vf0 = *(const short8*)&vr[q8];
            short8 vf1 = *(const short8*)&vr[32 + q8];
            oacc[dt] = __builtin_amdgcn_mfma_f32_16x16x32_bf16(pf0, vf0, oacc[dt], 0, 0, 0);
            oacc[dt] = __builtin_amdgcn_mfma_f32_16x16x32_bf16(pf1, vf1, oacc[dt], 0, 0, 0);
        }
    }

    // ---- denominator: reduce across quads (qrow = lm in every quad) ----
    lp += __shfl_xor(lp, 16);
    lp += __shfl_xor(lp, 32);
    if (quad == 0)
        Lpart[((size_t)seg * n + row0 + lm) * QHEADS + qh] = lp;

    // ---- unnormalized partial O:  O[qrow=q4+r][d=dt*16+lm] ----
    #pragma unroll
    for (int dt = 0; dt < 4; ++dt)
        #pragma unroll
        for (int r = 0; r < 4; ++r)
            Opart[((size_t)seg * n + row0 + q4 + r) * EDIM + qh * HDIM + dt * 16 + lm] =
                oacc[dt][r];
}

// ===========================================================================
// Kernel 5: combine segments + LayerNorm, fused. One block per row.
// ===========================================================================
__global__ __launch_bounds__(256)
void combine_ln(const float* __restrict__ Opart, const float* __restrict__ Lpart,
                const float* __restrict__ gamma, const float* __restrict__ beta,
                float* __restrict__ out, int n)
{
    const int r = blockIdx.x;
    const int t = threadIdx.x;

    __shared__ float linv[QHEADS];
    if (t < QHEADS) {
        float l = 0.f;
        #pragma unroll
        for (int s = 0; s < NSEG; ++s)
            l += Lpart[((size_t)s * n + r) * QHEADS + t];
        linv[t] = 1.0f / l;
    }
    __syncthreads();

    const int c = t * 4;
    float4 o = {0.f, 0.f, 0.f, 0.f};
    #pragma unroll
    for (int s = 0; s < NSEG; ++s) {
        float4 p = *(const float4*)&Opart[((size_t)s * n + r) * EDIM + c];
        o.x += p.x; o.y += p.y; o.z += p.z; o.w += p.w;
    }
    const float inv = linv[c >> 6];
    o.x *= inv; o.y *= inv; o.z *= inv; o.w *= inv;

    float s  = o.x + o.y + o.z + o.w;
    float sq = o.x * o.x + o.y * o.y + o.z * o.z + o.w * o.w;
    #pragma unroll
    for (int m = 1; m < 64; m <<= 1) {
        s  += __shfl_xor(s,  m);
        sq += __shfl_xor(sq, m);
    }
    __shared__ float ws_[4], wq_[4];
    const int wave = t >> 6;
    if ((t & 63) == 0) { ws_[wave] = s; wq_[wave] = sq; }
    __syncthreads();
    s  = ws_[0] + ws_[1] + ws_[2] + ws_[3];
    sq = wq_[0] + wq_[1] + wq_[2] + wq_[3];

    const float mu   = s * (1.f / EDIM);
    const float var  = sq * (1.f / EDIM) - mu * mu;
    const float rstd = rsqrtf(var + 1e-5f);

    float4 g = *(const float4*)&gamma[c];
    float4 b = *(const float4*)&beta[c];
    float4 y;
    y.x = (o.x - mu) * rstd * g.x + b.x;
    y.y = (o.y - mu) * rstd * g.y + b.y;
    y.z = (o.z - mu) * rstd * g.z + b.z;
    y.w = (o.w - mu) * rstd * g.w + b.w;
    *(float4*)&out[(size_t)r * EDIM + c] = y;
}

// ---------------------------------------------------------------------------
extern "C" void kernel_launch(void* const* d_in, const int* in_sizes, int n_in,
                              void* d_out, int out_size, void* d_ws, size_t ws_size,
                              hipStream_t stream)
{
    const float* query = (const float*)d_in[0];
    const float* key   = (const float*)d_in[1];
    const float* value = (const float*)d_in[2];
    const float* Wq    = (const float*)d_in[3];
    const float* bq    = (const float*)d_in[4];
    const float* Wk    = (const float*)d_in[5];
    const float* bk    = (const float*)d_in[6];
    const float* Wv    = (const float*)d_in[7];
    const float* bv    = (const float*)d_in[8];
    const float* gamma = (const float*)d_in[9];
    const float* beta  = (const float*)d_in[10];
    float* out = (float*)d_out;

    int n = in_sizes[0] / EDIM;   // 2048

    // workspace layout
    short* qa  = (short*)d_ws;                 // query bf16  n*1024
    short* ka  = qa  + (size_t)n * EDIM;
    short* va  = ka  + (size_t)n * EDIM;
    short* wqb = va  + (size_t)n * EDIM;       // weights bf16
    short* wkb = wqb + (size_t)EDIM * EDIM;
    short* wvb = wkb + (size_t)KVEDIM * EDIM;
    short* qb  = wvb + (size_t)KVEDIM * EDIM;  // projections bf16
    short* kb  = qb  + (size_t)n * EDIM;
    short* vb  = kb  + (size_t)n * KVEDIM;
    short* vtw = vb  + (size_t)n * KVEDIM;     // v transposed (256 x n)
    float* Opart = (float*)(vtw + (size_t)KVEDIM * n);  // NSEG x n x 1024
    float* Lpart = Opart + (size_t)NSEG * n * EDIM;     // NSEG x n x 16

    float qscale = 0.125f * 1.44269504088896f;  // 1/sqrt(64) * log2(e)

    cvt_bf16<<<dim3(512), 256, 0, stream>>>(query, key, value, Wq, Wk, Wv,
                                            qa, ka, va, wqb, wkb, wvb, n);

    proj_gemm<<<dim3(384), 256, 0, stream>>>(qa, ka, va, wqb, wkb, wvb,
                                             bq, bk, bv, qb, kb, vb, qscale);

    vt_kernel<<<dim3((n / 64) * 4), 256, 0, stream>>>(vb, vtw, n);

    attn_wave<<<dim3(n / 64, QHEADS, NSEG), 256, 0, stream>>>(
        qb, kb, vtw, Opart, Lpart, n);

    combine_ln<<<dim3(n), 256, 0, stream>>>(Opart, Lpart, gamma, beta, out, n);
}